// Round 5
// baseline (113.413 us; speedup 1.0000x reference)
//
#include <hip/hip_runtime.h>
#include <math.h>

#define B_ROWS 4096
#define D_DIM  2048
#define SIM_BLOCKS (B_ROWS / 2)          // 2 rows per block
#define PAIR_BLOCKS 512
#define ROWS_PER_PAIR_BLOCK (B_ROWS / PAIR_BLOCKS)   // 8
#define MARGIN_F 0.05f
#define HUBER_DELTA_F 0.1f
#define COS_EPS_F 1e-8f

// Native clang vector type: __builtin_nontemporal_load requires an ext-vector
// (HIP's float4 is a class and is rejected — R4 compile error).
typedef float v4f __attribute__((ext_vector_type(4)));

// Kernel A: 2 rows per block (8 independent 16B loads in flight per thread
// for latency hiding). Nontemporal loads: z_ref/z_perf are streamed exactly
// once — no point caching 64 MiB in L2. No atomics (R2 lesson: same-address
// atomicAdd serializes at L2, ~100 µs for 4096 blocks).
__global__ __launch_bounds__(256) void sim_huber_kernel(
    const float* __restrict__ z_ref, const float* __restrict__ z_perf,
    const float* __restrict__ pred, const float* __restrict__ tgt,
    float* __restrict__ sim, float* __restrict__ overall,
    float* __restrict__ hub_part)
{
    const int r0 = blockIdx.x * 2;
    const int tid = threadIdx.x;

    float dot[2] = {0.f, 0.f}, na2[2] = {0.f, 0.f}, nb2[2] = {0.f, 0.f};
    #pragma unroll
    for (int r = 0; r < 2; ++r) {
        const v4f* a4 = (const v4f*)(z_ref  + (size_t)(r0 + r) * D_DIM);
        const v4f* b4 = (const v4f*)(z_perf + (size_t)(r0 + r) * D_DIM);
        #pragma unroll
        for (int k = 0; k < 2; ++k) {
            const int idx = tid + k * 256;           // 512 x 16B per row
            v4f a = __builtin_nontemporal_load(&a4[idx]);
            v4f b = __builtin_nontemporal_load(&b4[idx]);
            dot[r] += a.x*b.x + a.y*b.y + a.z*b.z + a.w*b.w;
            na2[r] += a.x*a.x + a.y*a.y + a.z*a.z + a.w*a.w;
            nb2[r] += b.x*b.x + b.y*b.y + b.z*b.z + b.w*b.w;
        }
    }

    // Huber partials: 2 rows x 4 score elements
    __shared__ float hs[8];
    if (tid < 8) {
        const int r = r0 + (tid >> 2), c = tid & 3;
        float d  = pred[r * 4 + c] - tgt[r * 5 + c];
        float ad = fabsf(d);
        hs[tid] = (ad <= HUBER_DELTA_F) ? 0.5f * d * d
                                        : HUBER_DELTA_F * (ad - 0.5f * HUBER_DELTA_F);
    }

    const int lane = tid & 63, wave = tid >> 6;
    #pragma unroll
    for (int off = 32; off > 0; off >>= 1) {
        #pragma unroll
        for (int r = 0; r < 2; ++r) {
            dot[r] += __shfl_down(dot[r], off, 64);
            na2[r] += __shfl_down(na2[r], off, 64);
            nb2[r] += __shfl_down(nb2[r], off, 64);
        }
    }
    __shared__ float shm[2][3][4];
    if (lane == 0) {
        #pragma unroll
        for (int r = 0; r < 2; ++r) {
            shm[r][0][wave] = dot[r];
            shm[r][1][wave] = na2[r];
            shm[r][2][wave] = nb2[r];
        }
    }
    __syncthreads();
    if (tid < 2) {                                   // thread r finalizes row r0+r
        const int r = tid;
        float dt = shm[r][0][0] + shm[r][0][1] + shm[r][0][2] + shm[r][0][3];
        float na = sqrtf(shm[r][1][0] + shm[r][1][1] + shm[r][1][2] + shm[r][1][3]);
        float nb = sqrtf(shm[r][2][0] + shm[r][2][1] + shm[r][2][2] + shm[r][2][3]);
        na = fmaxf(na, COS_EPS_F);
        nb = fmaxf(nb, COS_EPS_F);
        sim[r0 + r]      = dt / (na * nb);
        overall[r0 + r]  = tgt[(r0 + r) * 5 + 4];
        hub_part[r0 + r] = hs[r*4+0] + hs[r*4+1] + hs[r*4+2] + hs[r*4+3];
    }
}

// Kernel B: 512 blocks x 8 i-rows. sim/overall staged once into LDS (32 KB),
// each LDS j-read amortized over 8 i-rows held in registers. 2 blocks/CU ->
// 8 waves/CU to hide LDS latency. Unique output slots — no atomics.
__global__ __launch_bounds__(256) void pair_kernel(
    const float* __restrict__ sim, const float* __restrict__ overall,
    float* __restrict__ pair_part, unsigned int* __restrict__ cnt_part)
{
    __shared__ float ls[B_ROWS];
    __shared__ float lo[B_ROWS];
    const int tid = threadIdx.x;

    const float4* s4 = (const float4*)sim;
    const float4* o4 = (const float4*)overall;
    float4* ls4 = (float4*)ls;
    float4* lo4 = (float4*)lo;
    #pragma unroll
    for (int k = 0; k < (B_ROWS / 4) / 256; ++k) {   // 4 iters
        const int idx = tid + k * 256;
        ls4[idx] = s4[idx];
        lo4[idx] = o4[idx];
    }
    __syncthreads();

    const int i0 = blockIdx.x * ROWS_PER_PAIR_BLOCK;
    float s_i[ROWS_PER_PAIR_BLOCK], o_i[ROWS_PER_PAIR_BLOCK];
    #pragma unroll
    for (int ii = 0; ii < ROWS_PER_PAIR_BLOCK; ++ii) {
        s_i[ii] = ls[i0 + ii];                       // broadcast reads, conflict-free
        o_i[ii] = lo[i0 + ii];
    }

    float part = 0.f;
    unsigned int cnt = 0;
    for (int j = tid; j < B_ROWS; j += 256) {        // 16 iters
        float sj = ls[j];
        float oj = lo[j];
        #pragma unroll
        for (int ii = 0; ii < ROWS_PER_PAIR_BLOCK; ++ii) {
            if (o_i[ii] > oj) {
                part += fmaxf(sj - s_i[ii] + MARGIN_F, 0.f);
                cnt++;
            }
        }
    }

    const int lane = tid & 63, wave = tid >> 6;
    #pragma unroll
    for (int off = 32; off > 0; off >>= 1) {
        part += __shfl_down(part, off, 64);
        cnt  += __shfl_down(cnt,  off, 64);
    }
    __shared__ float pw[4];
    __shared__ unsigned int cw[4];
    if (lane == 0) { pw[wave] = part; cw[wave] = cnt; }
    __syncthreads();
    if (tid == 0) {
        pair_part[blockIdx.x] = pw[0] + pw[1] + pw[2] + pw[3];
        cnt_part[blockIdx.x]  = cw[0] + cw[1] + cw[2] + cw[3];
    }
}

// Kernel C: single block reduces all partials and writes the 3 outputs.
__global__ __launch_bounds__(256) void finalize_kernel(
    const float* __restrict__ hub_part, const float* __restrict__ pair_part,
    const unsigned int* __restrict__ cnt_part, float* __restrict__ out)
{
    const int tid = threadIdx.x;
    float hub = 0.f, pr = 0.f;
    unsigned int cnt = 0;
    for (int k = tid; k < B_ROWS; k += 256) hub += hub_part[k];
    for (int k = tid; k < PAIR_BLOCKS; k += 256) {
        pr  += pair_part[k];
        cnt += cnt_part[k];
    }

    const int lane = tid & 63, wave = tid >> 6;
    #pragma unroll
    for (int off = 32; off > 0; off >>= 1) {
        hub += __shfl_down(hub, off, 64);
        pr  += __shfl_down(pr,  off, 64);
        cnt += __shfl_down(cnt, off, 64);
    }
    __shared__ float hw[4], pw[4];
    __shared__ unsigned int cw[4];
    if (lane == 0) { hw[wave] = hub; pw[wave] = pr; cw[wave] = cnt; }
    __syncthreads();
    if (tid == 0) {
        float H = hw[0] + hw[1] + hw[2] + hw[3];
        float P = pw[0] + pw[1] + pw[2] + pw[3];
        unsigned int C = cw[0] + cw[1] + cw[2] + cw[3];
        float n   = (float)C;
        float L_c = (n > 0.f) ? P / fmaxf(n, 1.f) : 0.f;
        float L_s = H / (float)(B_ROWS * 4);
        out[0] = L_c + L_s;
        out[1] = L_c;
        out[2] = L_s;
    }
}

extern "C" void kernel_launch(void* const* d_in, const int* in_sizes, int n_in,
                              void* d_out, int out_size, void* d_ws, size_t ws_size,
                              hipStream_t stream) {
    const float* z_ref  = (const float*)d_in[0];
    const float* z_perf = (const float*)d_in[1];
    const float* pred   = (const float*)d_in[2];
    const float* tgt    = (const float*)d_in[3];
    float* out = (float*)d_out;

    // Workspace layout (floats) — every slot written unconditionally each call:
    // [0,4096)=sim  [4096,8192)=overall  [8192,12288)=hub_part
    // [12288,12800)=pair_part  [12800,13312)=cnt_part (uint bits)
    float* ws        = (float*)d_ws;
    float* sim       = ws;
    float* overall   = ws + B_ROWS;
    float* hub_part  = ws + 2 * B_ROWS;
    float* pair_part = ws + 3 * B_ROWS;
    unsigned int* cnt_part = (unsigned int*)(ws + 3 * B_ROWS + PAIR_BLOCKS);

    sim_huber_kernel<<<SIM_BLOCKS, 256, 0, stream>>>(z_ref, z_perf, pred, tgt,
                                                     sim, overall, hub_part);
    pair_kernel<<<PAIR_BLOCKS, 256, 0, stream>>>(sim, overall, pair_part, cnt_part);
    finalize_kernel<<<1, 256, 0, stream>>>(hub_part, pair_part, cnt_part, out);
}

// Round 6
// 109.569 us; speedup vs baseline: 1.0351x; 1.0351x over previous
//
#include <hip/hip_runtime.h>
#include <math.h>

#define B_ROWS 4096
#define D_DIM  2048
#define SIM_BLOCKS (B_ROWS / 4)          // 4 waves/block, one row per wave
#define PAIR_BLOCKS 1024
#define ROWS_PER_PAIR_BLOCK (B_ROWS / PAIR_BLOCKS)   // 4
#define MARGIN_F 0.05f
#define HUBER_DELTA_F 0.1f
#define COS_EPS_F 1e-8f

// Kernel A: ONE WAVE PER ROW. Each lane: 8 float4 loads per array (16
// outstanding 16B loads, 256 B/lane in flight), pure shuffle reduction —
// no LDS, no __syncthreads. Huber folded into lanes 0-3 of the same wave.
// No atomics (R2: same-address atomicAdd serializes at L2 ≈ 100 µs).
__global__ __launch_bounds__(256) void sim_huber_kernel(
    const float* __restrict__ z_ref, const float* __restrict__ z_perf,
    const float* __restrict__ pred, const float* __restrict__ tgt,
    float* __restrict__ sim, float* __restrict__ overall,
    float* __restrict__ hub_part)
{
    const int wave = threadIdx.x >> 6;
    const int lane = threadIdx.x & 63;
    const int row  = blockIdx.x * 4 + wave;

    const float4* a4 = (const float4*)(z_ref  + (size_t)row * D_DIM);
    const float4* b4 = (const float4*)(z_perf + (size_t)row * D_DIM);

    float dot = 0.f, na2 = 0.f, nb2 = 0.f;
    #pragma unroll
    for (int k = 0; k < 8; ++k) {                    // 512 float4 / 64 lanes
        float4 a = a4[lane + k * 64];
        float4 b = b4[lane + k * 64];
        dot += a.x*b.x + a.y*b.y + a.z*b.z + a.w*b.w;
        na2 += a.x*a.x + a.y*a.y + a.z*a.z + a.w*a.w;
        nb2 += b.x*b.x + b.y*b.y + b.z*b.z + b.w*b.w;
    }

    // Huber partial: lanes 0-3 each handle one score element of this row.
    float h = 0.f;
    if (lane < 4) {
        float d  = pred[row * 4 + lane] - tgt[row * 5 + lane];
        float ad = fabsf(d);
        h = (ad <= HUBER_DELTA_F) ? 0.5f * d * d
                                  : HUBER_DELTA_F * (ad - 0.5f * HUBER_DELTA_F);
    }
    h += __shfl_down(h, 2, 64);
    h += __shfl_down(h, 1, 64);                      // lane 0: h0+h1+h2+h3

    #pragma unroll
    for (int off = 32; off > 0; off >>= 1) {
        dot += __shfl_down(dot, off, 64);
        na2 += __shfl_down(na2, off, 64);
        nb2 += __shfl_down(nb2, off, 64);
    }

    if (lane == 0) {
        float na = fmaxf(sqrtf(na2), COS_EPS_F);
        float nb = fmaxf(sqrtf(nb2), COS_EPS_F);
        sim[row]      = dot / (na * nb);
        overall[row]  = tgt[row * 5 + 4];
        hub_part[row] = h;
    }
}

// Kernel B (R3-exact, measured good): 1024 blocks x 4 i-rows. sim/overall
// staged once into 32 KB LDS; each LDS j-read amortized over 4 i-rows in
// registers. Unique output slots — no atomics.
__global__ __launch_bounds__(256) void pair_kernel(
    const float* __restrict__ sim, const float* __restrict__ overall,
    float* __restrict__ pair_part, unsigned int* __restrict__ cnt_part)
{
    __shared__ float ls[B_ROWS];
    __shared__ float lo[B_ROWS];
    const int tid = threadIdx.x;

    const float4* s4 = (const float4*)sim;
    const float4* o4 = (const float4*)overall;
    float4* ls4 = (float4*)ls;
    float4* lo4 = (float4*)lo;
    #pragma unroll
    for (int k = 0; k < (B_ROWS / 4) / 256; ++k) {   // 4 iters
        const int idx = tid + k * 256;
        ls4[idx] = s4[idx];
        lo4[idx] = o4[idx];
    }
    __syncthreads();

    const int i0 = blockIdx.x * ROWS_PER_PAIR_BLOCK;
    float s_i[ROWS_PER_PAIR_BLOCK], o_i[ROWS_PER_PAIR_BLOCK];
    #pragma unroll
    for (int ii = 0; ii < ROWS_PER_PAIR_BLOCK; ++ii) {
        s_i[ii] = ls[i0 + ii];                       // broadcast reads, conflict-free
        o_i[ii] = lo[i0 + ii];
    }

    float part = 0.f;
    unsigned int cnt = 0;
    for (int j = tid; j < B_ROWS; j += 256) {        // 16 iters
        float sj = ls[j];
        float oj = lo[j];
        #pragma unroll
        for (int ii = 0; ii < ROWS_PER_PAIR_BLOCK; ++ii) {
            if (o_i[ii] > oj) {
                part += fmaxf(sj - s_i[ii] + MARGIN_F, 0.f);
                cnt++;
            }
        }
    }

    const int lane = tid & 63, wave = tid >> 6;
    #pragma unroll
    for (int off = 32; off > 0; off >>= 1) {
        part += __shfl_down(part, off, 64);
        cnt  += __shfl_down(cnt,  off, 64);
    }
    __shared__ float pw[4];
    __shared__ unsigned int cw[4];
    if (lane == 0) { pw[wave] = part; cw[wave] = cnt; }
    __syncthreads();
    if (tid == 0) {
        pair_part[blockIdx.x] = pw[0] + pw[1] + pw[2] + pw[3];
        cnt_part[blockIdx.x]  = cw[0] + cw[1] + cw[2] + cw[3];
    }
}

// Kernel C: single block reduces all partials and writes the 3 outputs.
__global__ __launch_bounds__(256) void finalize_kernel(
    const float* __restrict__ hub_part, const float* __restrict__ pair_part,
    const unsigned int* __restrict__ cnt_part, float* __restrict__ out)
{
    const int tid = threadIdx.x;
    float hub = 0.f, pr = 0.f;
    unsigned int cnt = 0;
    for (int k = tid; k < B_ROWS; k += 256) hub += hub_part[k];
    for (int k = tid; k < PAIR_BLOCKS; k += 256) {
        pr  += pair_part[k];
        cnt += cnt_part[k];
    }

    const int lane = tid & 63, wave = tid >> 6;
    #pragma unroll
    for (int off = 32; off > 0; off >>= 1) {
        hub += __shfl_down(hub, off, 64);
        pr  += __shfl_down(pr,  off, 64);
        cnt += __shfl_down(cnt, off, 64);
    }
    __shared__ float hw[4], pw[4];
    __shared__ unsigned int cw[4];
    if (lane == 0) { hw[wave] = hub; pw[wave] = pr; cw[wave] = cnt; }
    __syncthreads();
    if (tid == 0) {
        float H = hw[0] + hw[1] + hw[2] + hw[3];
        float P = pw[0] + pw[1] + pw[2] + pw[3];
        unsigned int C = cw[0] + cw[1] + cw[2] + cw[3];
        float n   = (float)C;
        float L_c = (n > 0.f) ? P / fmaxf(n, 1.f) : 0.f;
        float L_s = H / (float)(B_ROWS * 4);
        out[0] = L_c + L_s;
        out[1] = L_c;
        out[2] = L_s;
    }
}

extern "C" void kernel_launch(void* const* d_in, const int* in_sizes, int n_in,
                              void* d_out, int out_size, void* d_ws, size_t ws_size,
                              hipStream_t stream) {
    const float* z_ref  = (const float*)d_in[0];
    const float* z_perf = (const float*)d_in[1];
    const float* pred   = (const float*)d_in[2];
    const float* tgt    = (const float*)d_in[3];
    float* out = (float*)d_out;

    // Workspace layout (floats) — every slot written unconditionally each call:
    // [0,4096)=sim  [4096,8192)=overall  [8192,12288)=hub_part
    // [12288,13312)=pair_part  [13312,14336)=cnt_part (uint bits)
    float* ws        = (float*)d_ws;
    float* sim       = ws;
    float* overall   = ws + B_ROWS;
    float* hub_part  = ws + 2 * B_ROWS;
    float* pair_part = ws + 3 * B_ROWS;
    unsigned int* cnt_part = (unsigned int*)(ws + 3 * B_ROWS + PAIR_BLOCKS);

    sim_huber_kernel<<<SIM_BLOCKS, 256, 0, stream>>>(z_ref, z_perf, pred, tgt,
                                                     sim, overall, hub_part);
    pair_kernel<<<PAIR_BLOCKS, 256, 0, stream>>>(sim, overall, pair_part, cnt_part);
    finalize_kernel<<<1, 256, 0, stream>>>(hub_part, pair_part, cnt_part, out);
}